// Round 7
// baseline (12079.440 us; speedup 1.0000x reference)
//
#include <hip/hip_runtime.h>
#include <stdint.h>

// GRU acoustic model, fp32 I/O. R7: proven agent-atomic sync + 2-chain
// latency hiding, no spills.
// R6 post-mortem: (a) sc0-only asm loads don't guarantee L1 bypass on
// gfx950 -> stale-tag infinite spin (hang); (b) dynamic XCD team formation
// had an exit race -> missing cluster -> partner poll hang. R7 reverts to
// __hip_atomic relaxed agent tagged words (R3/R5-proven) and a STATIC
// blockIdx mapping: 8 WGs = 2 teams x 4 clusters, 5 waves each, one
// 16-col slice per wave (<=246 VGPR, no spill). Each team interleaves two
// independent batch-group chains (A,B): compute+publish A, compute+publish
// B (~400cyc), then fetch A/B partner slices -- the L3 round trip of A's
// publishes is hidden under B's compute. Monotone tags (t<<16|bf16),
// parity double-buffer; provably race- and deadlock-free.
#define FEAT 13
#define EMB 300
#define BATCH 64
#define TSTEPS 2048
#define LPAD 328             // LDS row stride (u16)
#define XCOL 304             // x folded at K cols 304..316
#define KCOLS 320            // tagged hbuf row width (u32)
#define BUFW (16 * LPAD)     // u16 per parity LDS buffer
#define NGROUP 4

typedef float  floatx4 __attribute__((ext_vector_type(4)));
typedef short  shortx8 __attribute__((ext_vector_type(8)));

// workspace: tagged hbuf u32[2 parity][4 group][16 row][KCOLS]
#define WS_WORDS (2 * NGROUP * 16 * KCOLS)

__device__ __forceinline__ uint16_t f2b(float f) {
  union { float f; uint32_t i; } c; c.f = f;
  uint32_t r = c.i + 0x7fffu + ((c.i >> 16) & 1u);
  return (uint16_t)(r >> 16);
}
__device__ __forceinline__ float sigf(float x) {
  return __builtin_amdgcn_rcpf(1.f + __expf(-x));
}
__device__ __forceinline__ float tanhf_(float x) {
  return 1.f - 2.f * __builtin_amdgcn_rcpf(1.f + __expf(2.f * x));
}

__global__ void gru_init(uint32_t* __restrict__ ws) {
  int stride = gridDim.x * blockDim.x;
  for (int i = blockIdx.x * blockDim.x + threadIdx.x; i < WS_WORDS; i += stride)
    ws[i] = 0;  // clears 0xAA poison; tags never match (first poll wants 1)
}

// B-frag builders (one-time). mode 0: Whh + folded Wih; 1: Whh only;
// 2: folded Wih only (kt==9).
__device__ __forceinline__ shortx8 bfrag(const float* __restrict__ Whh,
                                         const float* __restrict__ Wih,
                                         int R, int kt, int q, int mode) {
  union { uint16_t u[8]; shortx8 v; } c;
  int k0 = kt * 32 + q * 8;
#pragma unroll
  for (int e = 0; e < 8; ++e) {
    int k = k0 + e;
    float val = 0.f;
    if (mode != 2 && k < EMB) val = Whh[R * EMB + k];
    if (mode != 1 && k >= XCOL && k < XCOL + FEAT) val = Wih[R * FEAT + (k - XCOL)];
    c.u[e] = f2b(val);
  }
  return c.v;
}
__device__ __forceinline__ shortx8 bfrag_fc(const float* __restrict__ W,
                                            int row, int kt, int q) {
  union { uint16_t u[8]; shortx8 v; } c;
  int k0 = kt * 32 + q * 8;
#pragma unroll
  for (int e = 0; e < 8; ++e) {
    int k = k0 + e;
    c.u[e] = f2b(k < EMB ? W[row * EMB + k] : 0.f);
  }
  return c.v;
}

#define MFMA16(A, B, C) __builtin_amdgcn_mfma_f32_16x16x32_bf16(A, B, C, 0, 0, 0)

// Tagged fetch of one partner region into LDS (agent atomics, whole-batch
// retry). PERLANE=10 -> 80 cols; PERLANE=8 -> 64 cols (cluster 3, c0=240).
template <int PERLANE>
__device__ __forceinline__ void fetch_region(
    const unsigned long long* __restrict__ src, uint16_t* __restrict__ wb,
    int c0, int lane, uint32_t t) {
  const int row = lane & 15, qq = lane >> 4;
  const unsigned long long* ap = src + (size_t)row * (KCOLS / 2) + qq * PERLANE;
  const unsigned long long TT =
      (((unsigned long long)t) << 16) | (((unsigned long long)t) << 48);
  unsigned long long v[PERLANE];
  while (true) {
#pragma unroll
    for (int i = 0; i < PERLANE; ++i)
      v[i] = __hip_atomic_load(ap + i, __ATOMIC_RELAXED,
                               __HIP_MEMORY_SCOPE_AGENT);
    unsigned long long bad = 0;
#pragma unroll
    for (int i = 0; i < PERLANE; ++i) bad |= (v[i] ^ TT);
    if (!__any((bad & 0xFFFF0000FFFF0000ULL) != 0ULL)) break;
  }
#pragma unroll
  for (int i = 0; i < PERLANE; ++i) {
    uint32_t pk = __builtin_amdgcn_perm((uint32_t)(v[i] >> 32), (uint32_t)v[i],
                                        0x05040100u);
    *(uint32_t*)(wb + row * LPAD + c0 + 2 * (qq * PERLANE + i)) = pk;
  }
}

__launch_bounds__(320, 1)
__global__ void gru_enc(const float* __restrict__ x,     // [64][2048][13]
                        const float* __restrict__ eWih,  // [900][13]
                        const float* __restrict__ eWhh,  // [900][300]
                        const float* __restrict__ ebih,  // [900]
                        const float* __restrict__ ebhh,  // [900]
                        const float* __restrict__ fcW,   // [300][300]
                        const float* __restrict__ fcb,   // [300]
                        float* __restrict__ out,
                        uint32_t* __restrict__ hbuf) {
  __shared__ uint16_t hlds[2][2 * BUFW];   // [chain][parity*BUFW]

  const int tid = threadIdx.x, lane = tid & 63, w = tid >> 6;
  const int nl = lane & 15, q = lane >> 4;
  const int tc = blockIdx.x >> 2;     // team 0/1 -> groups 2tc, 2tc+1
  const int c  = blockIdx.x & 3;      // hidden cluster
  const int gA = 2 * tc, gB = 2 * tc + 1;

  const int jcol = 80 * c + 16 * w + nl;   // own gate/h column
  const bool jv = (jcol < EMB);
  const int j = jv ? jcol : 0;
  const bool dead = (c == 3 && w == 4);    // slice fully in pad: idle

  // ---- one-time: weight B-fragments into registers ----
  shortx8 Br[10], Bz[10], Bn[10], Bnx;
#pragma unroll
  for (int kt = 0; kt < 10; ++kt) {
    Br[kt] = bfrag(eWhh, eWih, 0 * EMB + j, kt, q, 0);
    Bz[kt] = bfrag(eWhh, eWih, 1 * EMB + j, kt, q, 0);
    Bn[kt] = bfrag(eWhh, eWih, 2 * EMB + j, kt, q, 1);
  }
  Bnx = bfrag(eWhh, eWih, 2 * EMB + j, 9, q, 2);
  const float br = ebih[j] + ebhh[j];
  const float bz = ebih[EMB + j] + ebhh[EMB + j];
  const float bin = ebih[2 * EMB + j], bhn = ebhh[2 * EMB + j];

  // ---- init LDS (all 4 buffers), stage x_0 for both chains ----
  for (int i = tid; i < 2 * BUFW; i += 320) { hlds[0][i] = 0; hlds[1][i] = 0; }
  __syncthreads();
  for (int i = tid; i < 16 * FEAT; i += 320) {
    int m = i / FEAT, f = i - m * FEAT;
    hlds[0][m * LPAD + XCOL + f] =
        f2b(x[((size_t)(gA * 16 + m) * TSTEPS) * FEAT + f]);
    hlds[1][m * LPAD + XCOL + f] =
        f2b(x[((size_t)(gB * 16 + m) * TSTEPS) * FEAT + f]);
  }
  __syncthreads();

  float hA[4] = {0.f, 0.f, 0.f, 0.f};
  float hB[4] = {0.f, 0.f, 0.f, 0.f};

  // ================= recurrence: 1 barrier/step =================
  for (int t = 1; t <= TSTEPS; ++t) {
    const int p = (t - 1) & 1, pn = p ^ 1;
    const uint32_t tg = ((uint32_t)t) << 16;

    // compute+publish one chain (A-frags -> 31 MFMA -> gates -> tagged pub)
    auto do_chain = [&](const uint16_t* rb, uint16_t* wbuf, uint32_t* gbase,
                        float* hp) {
      const uint16_t* arow = rb + nl * LPAD + q * 8;
      floatx4 ar = {0.f,0.f,0.f,0.f}, az = {0.f,0.f,0.f,0.f};
      floatx4 anh = {0.f,0.f,0.f,0.f}, anx = {0.f,0.f,0.f,0.f};
      shortx8 A9;
#pragma unroll
      for (int kt = 0; kt < 10; ++kt) {
        shortx8 A = *(const shortx8*)(arow + kt * 32);
        ar  = MFMA16(A, Br[kt], ar);
        az  = MFMA16(A, Bz[kt], az);
        anh = MFMA16(A, Bn[kt], anh);
        if (kt == 9) A9 = A;
      }
      anx = MFMA16(A9, Bnx, anx);
      uint32_t* dst = gbase + (q * 4) * KCOLS + jcol;
#pragma unroll
      for (int i = 0; i < 4; ++i) {
        float r = sigf(ar[i] + br);
        float z = sigf(az[i] + bz);
        float n = tanhf_(anx[i] + bin + r * (anh[i] + bhn));
        float h = z * (hp[i] - n) + n;
        h = jv ? h : 0.f;       // pad cols publish tag|0
        hp[i] = h;
        uint16_t hb = f2b(h);
        __hip_atomic_store(dst + i * KCOLS, tg | hb, __ATOMIC_RELAXED,
                           __HIP_MEMORY_SCOPE_AGENT);
        if (jv) wbuf[(q * 4 + i) * LPAD + jcol] = hb;
      }
    };

    if (!dead) {
      do_chain(hlds[0] + p * BUFW, hlds[0] + pn * BUFW,
               hbuf + (size_t)((pn * NGROUP + gA) * 16) * KCOLS, hA);
      do_chain(hlds[1] + p * BUFW, hlds[1] + pn * BUFW,
               hbuf + (size_t)((pn * NGROUP + gB) * 16) * KCOLS, hB);
    }

    if (w < 3) {
      // fetch partner cluster pc's h_t for both chains (A first: its
      // publishes have had B's compute time to land)
      const int pc = w + (w >= c ? 1 : 0);
      const int c0 = 80 * pc;
      const unsigned long long* sA = (const unsigned long long*)
          (hbuf + (size_t)((pn * NGROUP + gA) * 16) * KCOLS) + c0 / 2;
      const unsigned long long* sB = (const unsigned long long*)
          (hbuf + (size_t)((pn * NGROUP + gB) * 16) * KCOLS) + c0 / 2;
      if (pc < 3) {
        fetch_region<10>(sA, hlds[0] + pn * BUFW, c0, lane, (uint32_t)t);
        fetch_region<10>(sB, hlds[1] + pn * BUFW, c0, lane, (uint32_t)t);
      } else {
        fetch_region<8>(sA, hlds[0] + pn * BUFW, c0, lane, (uint32_t)t);
        fetch_region<8>(sB, hlds[1] + pn * BUFW, c0, lane, (uint32_t)t);
      }
    } else if (w == 3 && t < TSTEPS) {
      // stage x_t for both chains into buf pn (consumed at t+1)
      for (int i = lane; i < 16 * FEAT; i += 64) {
        int m = i / FEAT, f = i - m * FEAT;
        hlds[0][pn * BUFW + m * LPAD + XCOL + f] =
            f2b(x[((size_t)(gA * 16 + m) * TSTEPS + t) * FEAT + f]);
        hlds[1][pn * BUFW + m * LPAD + XCOL + f] =
            f2b(x[((size_t)(gB * 16 + m) * TSTEPS + t) * FEAT + f]);
      }
    }
    __syncthreads();
  }

  // ================= fc: emb = relu(h_T @ fcW^T + fcb), both chains ======
  {
    float* oemb = out + (size_t)BATCH * TSTEPS * FEAT;
    for (int ch = 0; ch < 2; ++ch) {
      const uint16_t* arow = hlds[ch] + nl * LPAD + q * 8;  // parity 0 (T even)
      floatx4 ae = {0.f,0.f,0.f,0.f};
#pragma unroll
      for (int kt = 0; kt < 10; ++kt) {
        shortx8 A = *(const shortx8*)(arow + kt * 32);
        ae = MFMA16(A, bfrag_fc(fcW, j, kt, q), ae);
      }
      const float fb = fcb[j];
      const int gg = 2 * tc + ch;
#pragma unroll
      for (int i = 0; i < 4; ++i) {
        float e = ae[i] + fb;
        if (jv)
          oemb[(size_t)(gg * 16 + q * 4 + i) * EMB + jcol] = e > 0.f ? e : 0.f;
      }
    }
  }
}

// ---------------- decoder: 1 wave per batch, all fp32 ----------------
__launch_bounds__(64, 1)
__global__ void gru_dec(const float* __restrict__ dWih,  // [39][300]
                        const float* __restrict__ dWhh,  // [39][13]
                        const float* __restrict__ dbih,  // [39]
                        const float* __restrict__ dbhh,  // [39]
                        float* __restrict__ out) {
  const int b  = blockIdx.x;
  const int lj = threadIdx.x;            // [0,13)=r [13,26)=z [26,39)=n
  const float* emb = out + (size_t)BATCH * TSTEPS * FEAT + (size_t)b * EMB;

  float Wd[FEAT];
#pragma unroll
  for (int k = 0; k < FEAT; ++k) Wd[k] = 0.f;
  float bhhv = 0.f, dgi = 0.f;
  if (lj < 3 * FEAT) {
#pragma unroll
    for (int k = 0; k < FEAT; ++k) Wd[k] = dWhh[lj * FEAT + k];
    bhhv = dbhh[lj];
    dgi  = dbih[lj];
#pragma unroll 4
    for (int k = 0; k < EMB; ++k)
      dgi = fmaf(emb[k], dWih[lj * EMB + k], dgi);
  }

  float hrep[FEAT];
#pragma unroll
  for (int k = 0; k < FEAT; ++k) hrep[k] = 0.f;
  float hown = 0.f;
  const bool nlane = (lj >= 2 * FEAT && lj < 3 * FEAT);
  float* orow = out + (size_t)b * TSTEPS * FEAT;

  for (int t = 0; t < TSTEPS; ++t) {
    float gh = bhhv;
#pragma unroll
    for (int k = 0; k < FEAT; ++k) gh = fmaf(Wd[k], hrep[k], gh);
    float sg = sigf(dgi + gh);
    float rr = __shfl(sg, (lj - 2 * FEAT) & 63);
    float zz = __shfl(sg, (lj - FEAT) & 63);
    float nn = tanhf_(dgi + rr * gh);
    float hn = zz * (hown - nn) + nn;
    bool same = (!nlane) || (hn == hown);
    if (nlane) {
      orow[t * FEAT + (lj - 2 * FEAT)] = hn;
      hown = hn;
    }
#pragma unroll
    for (int k = 0; k < FEAT; ++k) hrep[k] = __shfl(hown, 2 * FEAT + k);
    if (__all(same)) {  // exact fp32 fixed point -> rest constant
      if (nlane) {
        for (int t2 = t + 1; t2 < TSTEPS; ++t2)
          orow[t2 * FEAT + (lj - 2 * FEAT)] = hn;
      }
      break;
    }
  }
}

extern "C" void kernel_launch(void* const* d_in, const int* in_sizes, int n_in,
                              void* d_out, int out_size, void* d_ws, size_t ws_size,
                              hipStream_t stream) {
  (void)in_sizes; (void)n_in; (void)out_size; (void)ws_size;
  const float* x    = (const float*)d_in[0];
  const float* eWih = (const float*)d_in[1];
  const float* eWhh = (const float*)d_in[2];
  const float* ebih = (const float*)d_in[3];
  const float* ebhh = (const float*)d_in[4];
  const float* fcW  = (const float*)d_in[5];
  const float* fcb  = (const float*)d_in[6];
  const float* dWih = (const float*)d_in[7];
  const float* dWhh = (const float*)d_in[8];
  const float* dbih = (const float*)d_in[9];
  const float* dbhh = (const float*)d_in[10];

  hipLaunchKernelGGL(gru_init, dim3(32), dim3(256), 0, stream, (uint32_t*)d_ws);
  hipLaunchKernelGGL(gru_enc, dim3(8), dim3(320), 0, stream,
                     x, eWih, eWhh, ebih, ebhh, fcW, fcb, (float*)d_out,
                     (uint32_t*)d_ws);
  hipLaunchKernelGGL(gru_dec, dim3(BATCH), dim3(64), 0, stream,
                     dWih, dWhh, dbih, dbhh, (float*)d_out);
}

// Round 8
// 5201.593 us; speedup vs baseline: 2.3223x; 2.3223x over previous
//
#include <hip/hip_runtime.h>
#include <stdint.h>

// GRU acoustic model, fp32 I/O. R8: ZERO cross-CU sync.
// R3-R7 post-mortems: every cross-CU h-exchange design costs 3.5-6us/step at
// the L3 coherence point (retry storms, placement-bimodal) or spills
// (VGPR cap). R8 puts each batch-group's entire recurrence on ONE CU:
// int8 Whh (fixed scale: bound=1/sqrt(300)) register-resident -- 288KB fits
// the 512KB RF where bf16's 548KB could not (R4). 4 WGs x 512 thr (8 waves,
// cap 256 VGPR): waves 0-4 two reg-slices, waves 5-7 two reg + one LDS-B
// slice (46KB wlds). h carried fp32 in regs (recurrent term), quantized to
// i8 only as MFMA input (|h|<1 strictly); x path bf16 MFMA (16x16x32).
// One __syncthreads per step. No atomics, no workspace, no fences.
// i8 A/B layout safety: A (h) and B (Whh) are packed with the IDENTICAL
// (lane,position)->k mapping; MFMA pairs operand positions, so the dot is
// correct for any consistent packing. C/D layout is shape-determined
// (col=lane&15, row=q*4+i), dtype-independent (verified m89/m121-128).
// Decoder: separate kernel, 1 wave/batch, fp32 shuffle GRU (proven R2-R7).
#define FEAT 13
#define EMB 300
#define BATCH 64
#define TSTEPS 2048
#define QW  2199.7045f      // 127*sqrt(300): w_q = rint(w*QW)
#define SWH 3.5795795e-6f   // dequant: (1/(127*sqrt(300))) * (1/127)

typedef float  floatx4 __attribute__((ext_vector_type(4)));
typedef short  shortx8 __attribute__((ext_vector_type(8)));
typedef int    intx4   __attribute__((ext_vector_type(4)));

__device__ __forceinline__ uint16_t f2b(float f) {
  union { float f; uint32_t i; } c; c.f = f;
  uint32_t r = c.i + 0x7fffu + ((c.i >> 16) & 1u);
  return (uint16_t)(r >> 16);
}
__device__ __forceinline__ float sigf(float x) {
  return __builtin_amdgcn_rcpf(1.f + __expf(-x));
}
__device__ __forceinline__ float tanhf_(float x) {
  return 1.f - 2.f * __builtin_amdgcn_rcpf(1.f + __expf(2.f * x));
}
__device__ __forceinline__ int q8w(float v) {
  return __float2int_rn(fminf(fmaxf(v * QW, -127.f), 127.f));
}

#define MFI8(A, B, C) __builtin_amdgcn_mfma_i32_16x16x64_i8(A, B, C, 0, 0, 0)
#define MFBF(A, B, C) __builtin_amdgcn_mfma_f32_16x16x32_bf16(A, B, C, 0, 0, 0)

__launch_bounds__(512, 2)
__global__ void gru_enc(const float* __restrict__ x,     // [64][2048][13]
                        const float* __restrict__ eWih,  // [900][13]
                        const float* __restrict__ eWhh,  // [900][300]
                        const float* __restrict__ ebih,  // [900]
                        const float* __restrict__ ebhh,  // [900]
                        const float* __restrict__ fcW,   // [300][300]
                        const float* __restrict__ fcb,   // [300]
                        float* __restrict__ out) {
  __shared__ __align__(16) signed char hbuf[2][16][320];    // h_t i8, K-pad 0
  __shared__ __align__(16) uint16_t    xt[2][16][32];       // x_t bf16, pad 0
  __shared__ __align__(16) signed char wlds[3][3][5][1024]; // slices 16-18 i8
  __shared__ __align__(16) float       blds[320][4];        // br,bz,bin,bhn

  const int tid = threadIdx.x, lane = tid & 63, w = tid >> 6;
  const int nl = lane & 15, q = lane >> 4;
  const int g = blockIdx.x;          // batch group (16 rows)

  const int  s0   = 2 * w;           // reg slices 2w, 2w+1  (0..15)
  const bool hasL = (w >= 5);        // + LDS slice 16+(w-5)
  const int  sL   = hasL ? (16 + (w - 5)) : 16;

  // ---------------- init LDS ----------------
  for (int i = tid; i < 2 * 16 * 320; i += 512) ((signed char*)hbuf)[i] = 0;
  for (int i = tid; i < 2 * 16 * 32; i += 512) ((uint16_t*)xt)[i] = 0;
  if (tid < 320) {
    int i = tid;
    float b0 = 0.f, b1 = 0.f, b2 = 0.f, b3 = 0.f;
    if (i < EMB) {
      b0 = ebih[i] + ebhh[i];
      b1 = ebih[EMB + i] + ebhh[EMB + i];
      b2 = ebih[2 * EMB + i];
      b3 = ebhh[2 * EMB + i];
    }
    blds[i][0] = b0; blds[i][1] = b1; blds[i][2] = b2; blds[i][3] = b3;
  }
  for (int i = tid; i < 16 * FEAT; i += 512) {   // x_0 -> xt[0]
    int m = i / FEAT, f = i - m * FEAT;
    xt[0][m][f] = f2b(x[((size_t)(g * 16 + m) * TSTEPS) * FEAT + f]);
  }
  if (hasL) {   // build LDS-B slice (one-time)
    for (int g3 = 0; g3 < 3; ++g3)
      for (int kt = 0; kt < 5; ++kt) {
        int jj = 16 * sL + nl;
        for (int e = 0; e < 16; ++e) {
          int k = kt * 64 + q * 16 + e;
          float v = (jj < EMB && k < EMB)
                        ? eWhh[((size_t)(g3 * EMB + jj)) * EMB + k] : 0.f;
          wlds[w - 5][g3][kt][lane * 16 + e] = (signed char)q8w(v);
        }
      }
  }

  // ---------------- one-time: register B-fragments ----------------
  intx4   Bh[2][3][5];   // i8 Whh frags [slice][gate][kt]
  shortx8 Bx[2][3];      // bf16 Wih frags
  shortx8 BxL[3];
#pragma unroll
  for (int sl = 0; sl < 2; ++sl) {
    int jj = 16 * (s0 + sl) + nl;
#pragma unroll
    for (int g3 = 0; g3 < 3; ++g3) {
#pragma unroll
      for (int kt = 0; kt < 5; ++kt) {
        int b[4] = {0, 0, 0, 0};
        for (int e = 0; e < 16; ++e) {
          int k = kt * 64 + q * 16 + e;
          float v = (jj < EMB && k < EMB)
                        ? eWhh[((size_t)(g3 * EMB + jj)) * EMB + k] : 0.f;
          b[e >> 2] |= (q8w(v) & 255) << ((e & 3) * 8);
        }
        intx4 t; t[0] = b[0]; t[1] = b[1]; t[2] = b[2]; t[3] = b[3];
        Bh[sl][g3][kt] = t;
      }
      union { uint16_t u[8]; shortx8 v; } c;
      for (int e = 0; e < 8; ++e) {
        int k = q * 8 + e;
        c.u[e] = (jj < EMB && k < FEAT)
                     ? f2b(eWih[(g3 * EMB + jj) * FEAT + k]) : (uint16_t)0;
      }
      Bx[sl][g3] = c.v;
    }
  }
  if (hasL) {
    int jj = 16 * sL + nl;
#pragma unroll
    for (int g3 = 0; g3 < 3; ++g3) {
      union { uint16_t u[8]; shortx8 v; } c;
      for (int e = 0; e < 8; ++e) {
        int k = q * 8 + e;
        c.u[e] = (jj < EMB && k < FEAT)
                     ? f2b(eWih[(g3 * EMB + jj) * FEAT + k]) : (uint16_t)0;
      }
      BxL[g3] = c.v;
    }
  }

  float hprev[2][4] = {{0.f,0.f,0.f,0.f},{0.f,0.f,0.f,0.f}};
  float hprevL[4]   = {0.f,0.f,0.f,0.f};
  __syncthreads();

  // ================= recurrence: 1 barrier/step, all on-CU =================
  for (int t = 1; t <= TSTEPS; ++t) {
    const int p = (t - 1) & 1, pn = t & 1;

    // shared A-frags (h_{t-1} i8, x_{t-1} bf16) — reused by all this wave's slices
    intx4 Ah[5];
#pragma unroll
    for (int kt = 0; kt < 5; ++kt)
      Ah[kt] = *(const intx4*)&hbuf[p][nl][kt * 64 + q * 16];
    shortx8 Ax = *(const shortx8*)&xt[p][nl][q * 8];

    if (w == 4 && t < TSTEPS) {   // stage x_t for step t+1
      for (int i = lane; i < 16 * FEAT; i += 64) {
        int m = i / FEAT, f = i - m * FEAT;
        xt[pn][m][f] = f2b(x[((size_t)(g * 16 + m) * TSTEPS + t) * FEAT + f]);
      }
    }

#pragma unroll
    for (int sl = 0; sl < 2; ++sl) {
      intx4 air = {0,0,0,0}, aiz = {0,0,0,0}, ain = {0,0,0,0};
#pragma unroll
      for (int kt = 0; kt < 5; ++kt) {
        air = MFI8(Ah[kt], Bh[sl][0][kt], air);
        aiz = MFI8(Ah[kt], Bh[sl][1][kt], aiz);
        ain = MFI8(Ah[kt], Bh[sl][2][kt], ain);
      }
      floatx4 axr = {0.f,0.f,0.f,0.f}, axz = {0.f,0.f,0.f,0.f}, axn = {0.f,0.f,0.f,0.f};
      axr = MFBF(Ax, Bx[sl][0], axr);
      axz = MFBF(Ax, Bx[sl][1], axz);
      axn = MFBF(Ax, Bx[sl][2], axn);
      int jj = 16 * (s0 + sl) + nl;
      floatx4 bias = *(const floatx4*)&blds[jj][0];
#pragma unroll
      for (int i = 0; i < 4; ++i) {
        float pr  = (float)air[i] * SWH + axr[i] + bias[0];
        float pz  = (float)aiz[i] * SWH + axz[i] + bias[1];
        float hn  = (float)ain[i] * SWH + bias[3];
        float in_ = axn[i] + bias[2];
        float r = sigf(pr), z = sigf(pz);
        float n = tanhf_(in_ + r * hn);
        float h = z * (hprev[sl][i] - n) + n;
        hprev[sl][i] = h;
        float hq = fminf(fmaxf(h * 127.f, -127.f), 127.f);
        hbuf[pn][q * 4 + i][jj] = (signed char)__float2int_rn(hq);
      }
    }
    if (hasL) {
      intx4 air = {0,0,0,0}, aiz = {0,0,0,0}, ain = {0,0,0,0};
#pragma unroll
      for (int kt = 0; kt < 5; ++kt) {
        intx4 b0 = *(const intx4*)&wlds[w - 5][0][kt][lane * 16];
        intx4 b1 = *(const intx4*)&wlds[w - 5][1][kt][lane * 16];
        intx4 b2 = *(const intx4*)&wlds[w - 5][2][kt][lane * 16];
        air = MFI8(Ah[kt], b0, air);
        aiz = MFI8(Ah[kt], b1, aiz);
        ain = MFI8(Ah[kt], b2, ain);
      }
      floatx4 axr = {0.f,0.f,0.f,0.f}, axz = {0.f,0.f,0.f,0.f}, axn = {0.f,0.f,0.f,0.f};
      axr = MFBF(Ax, BxL[0], axr);
      axz = MFBF(Ax, BxL[1], axz);
      axn = MFBF(Ax, BxL[2], axn);
      int jj = 16 * sL + nl;
      floatx4 bias = *(const floatx4*)&blds[jj][0];
#pragma unroll
      for (int i = 0; i < 4; ++i) {
        float pr  = (float)air[i] * SWH + axr[i] + bias[0];
        float pz  = (float)aiz[i] * SWH + axz[i] + bias[1];
        float hn  = (float)ain[i] * SWH + bias[3];
        float in_ = axn[i] + bias[2];
        float r = sigf(pr), z = sigf(pz);
        float n = tanhf_(in_ + r * hn);
        float h = z * (hprevL[i] - n) + n;   // pad cols: all-zero -> h stays 0
        hprevL[i] = h;
        float hq = fminf(fmaxf(h * 127.f, -127.f), 127.f);
        hbuf[pn][q * 4 + i][jj] = (signed char)__float2int_rn(hq);
      }
    }
    __syncthreads();
  }

  // ================= fc: emb = relu(h_T @ fcW^T + fcb) =================
  {
    float* oemb = out + (size_t)BATCH * TSTEPS * FEAT;
    intx4 AhT[5];
#pragma unroll
    for (int kt = 0; kt < 5; ++kt)
      AhT[kt] = *(const intx4*)&hbuf[0][nl][kt * 64 + q * 16];  // T even
    const int nsl = hasL ? 3 : 2;
    for (int u = 0; u < nsl; ++u) {
      int ss = (u < 2) ? (s0 + u) : sL;
      int jj = 16 * ss + nl;
      intx4 acc = {0, 0, 0, 0};
      for (int kt = 0; kt < 5; ++kt) {
        int b[4] = {0, 0, 0, 0};
        for (int e = 0; e < 16; ++e) {
          int k = kt * 64 + q * 16 + e;
          float v = (jj < EMB && k < EMB) ? fcW[(size_t)jj * EMB + k] : 0.f;
          b[e >> 2] |= (q8w(v) & 255) << ((e & 3) * 8);
        }
        intx4 bb; bb[0] = b[0]; bb[1] = b[1]; bb[2] = b[2]; bb[3] = b[3];
        acc = MFI8(AhT[kt], bb, acc);
      }
      if (jj < EMB) {
        float fb = fcb[jj];
#pragma unroll
        for (int i = 0; i < 4; ++i) {
          float e = (float)acc[i] * SWH + fb;
          oemb[(size_t)(g * 16 + q * 4 + i) * EMB + jj] = e > 0.f ? e : 0.f;
        }
      }
    }
  }
}

// ---------------- decoder: 1 wave per batch, all fp32 (proven) ----------------
__launch_bounds__(64, 1)
__global__ void gru_dec(const float* __restrict__ dWih,  // [39][300]
                        const float* __restrict__ dWhh,  // [39][13]
                        const float* __restrict__ dbih,  // [39]
                        const float* __restrict__ dbhh,  // [39]
                        float* __restrict__ out) {
  const int b  = blockIdx.x;
  const int lj = threadIdx.x;            // [0,13)=r [13,26)=z [26,39)=n
  const float* emb = out + (size_t)BATCH * TSTEPS * FEAT + (size_t)b * EMB;

  float Wd[FEAT];
#pragma unroll
  for (int k = 0; k < FEAT; ++k) Wd[k] = 0.f;
  float bhhv = 0.f, dgi = 0.f;
  if (lj < 3 * FEAT) {
#pragma unroll
    for (int k = 0; k < FEAT; ++k) Wd[k] = dWhh[lj * FEAT + k];
    bhhv = dbhh[lj];
    dgi  = dbih[lj];
#pragma unroll 4
    for (int k = 0; k < EMB; ++k)
      dgi = fmaf(emb[k], dWih[lj * EMB + k], dgi);
  }

  float hrep[FEAT];
#pragma unroll
  for (int k = 0; k < FEAT; ++k) hrep[k] = 0.f;
  float hown = 0.f;
  const bool nlane = (lj >= 2 * FEAT && lj < 3 * FEAT);
  float* orow = out + (size_t)b * TSTEPS * FEAT;

  for (int t = 0; t < TSTEPS; ++t) {
    float gh = bhhv;
#pragma unroll
    for (int k = 0; k < FEAT; ++k) gh = fmaf(Wd[k], hrep[k], gh);
    float sg = sigf(dgi + gh);
    float rr = __shfl(sg, (lj - 2 * FEAT) & 63);
    float zz = __shfl(sg, (lj - FEAT) & 63);
    float nn = tanhf_(dgi + rr * gh);
    float hn = zz * (hown - nn) + nn;
    bool same = (!nlane) || (hn == hown);
    if (nlane) {
      orow[t * FEAT + (lj - 2 * FEAT)] = hn;
      hown = hn;
    }
#pragma unroll
    for (int k = 0; k < FEAT; ++k) hrep[k] = __shfl(hown, 2 * FEAT + k);
    if (__all(same)) {  // exact fp32 fixed point -> rest constant
      if (nlane) {
        for (int t2 = t + 1; t2 < TSTEPS; ++t2)
          orow[t2 * FEAT + (lj - 2 * FEAT)] = hn;
      }
      break;
    }
  }
}

extern "C" void kernel_launch(void* const* d_in, const int* in_sizes, int n_in,
                              void* d_out, int out_size, void* d_ws, size_t ws_size,
                              hipStream_t stream) {
  (void)in_sizes; (void)n_in; (void)out_size; (void)d_ws; (void)ws_size;
  const float* x    = (const float*)d_in[0];
  const float* eWih = (const float*)d_in[1];
  const float* eWhh = (const float*)d_in[2];
  const float* ebih = (const float*)d_in[3];
  const float* ebhh = (const float*)d_in[4];
  const float* fcW  = (const float*)d_in[5];
  const float* fcb  = (const float*)d_in[6];
  const float* dWih = (const float*)d_in[7];
  const float* dWhh = (const float*)d_in[8];
  const float* dbih = (const float*)d_in[9];
  const float* dbhh = (const float*)d_in[10];

  hipLaunchKernelGGL(gru_enc, dim3(4), dim3(512), 0, stream,
                     x, eWih, eWhh, ebih, ebhh, fcW, fcb, (float*)d_out);
  hipLaunchKernelGGL(gru_dec, dim3(BATCH), dim3(64), 0, stream,
                     dWih, dWhh, dbih, dbhh, (float*)d_out);
}

// Round 9
// 4358.259 us; speedup vs baseline: 2.7716x; 1.1935x over previous
//
#include <hip/hip_runtime.h>
#include <stdint.h>

// GRU acoustic model, fp32 I/O. R9: 16 CUs x 4 batch rows, redistributed
// epilogue. R8 post-mortem: zero-sync on-CU design works (FETCH 9MB, no
// spill) but per-CU epilogue dominates: trans pipe ~900 cyc/CU/step for
// 16 rows x 300 cols x 3 gates, plus exec-masked epilogue waste and hasL
// wave imbalance. Batch rows are independent -> 16 WGs x 4 rows each.
// Weights as 57 gate-blocks (slice,gate): 7 register-blocks per wave
// (balanced; ~245 unified regs) + block 56 in LDS (wave 0). Per step:
// MFMA -> pre-activations(+bias) into conflict-free LDS scr[ch][row][col]
// -> barrier -> 512 lanes each own ~2.4 (row,col) elements (static, fp32
// hprev lane-resident) -> sigmoid/tanh/h -> i8 hbuf -> barrier. Zero
// cross-CU traffic; 2 barriers/step. fc fused (i8 MFMA); decoder kernel
// unchanged (proven R2-R8).
#define FEAT 13
#define EMB 300
#define BATCH 64
#define TSTEPS 2048
#define ROWS 4              // valid batch rows per WG
#define NCOL 304            // 19 slices x 16 gate cols (300 + 4 pad)
#define KI8 320             // i8 K per hbuf row (300 + pad)
#define NELEM (ROWS * NCOL) // 1216 redistributed elements
#define QW  2199.7045f      // 127*sqrt(300)
#define SWH 3.5795795e-6f   // 1/(127*127*sqrt(300))

typedef float  floatx4 __attribute__((ext_vector_type(4)));
typedef short  shortx8 __attribute__((ext_vector_type(8)));
typedef int    intx4   __attribute__((ext_vector_type(4)));

__device__ __forceinline__ uint16_t f2b(float f) {
  union { float f; uint32_t i; } c; c.f = f;
  uint32_t r = c.i + 0x7fffu + ((c.i >> 16) & 1u);
  return (uint16_t)(r >> 16);
}
__device__ __forceinline__ float sigf(float x) {
  return __builtin_amdgcn_rcpf(1.f + __expf(-x));
}
__device__ __forceinline__ float tanhf_(float x) {
  return 1.f - 2.f * __builtin_amdgcn_rcpf(1.f + __expf(2.f * x));
}
__device__ __forceinline__ int q8w(float v) {
  return __float2int_rn(fminf(fmaxf(v * QW, -127.f), 127.f));
}

#define MFI8(A, B, C) __builtin_amdgcn_mfma_i32_16x16x64_i8(A, B, C, 0, 0, 0)
#define MFBF(A, B, C) __builtin_amdgcn_mfma_f32_16x16x32_bf16(A, B, C, 0, 0, 0)

__launch_bounds__(512, 2)
__global__ void gru_enc(const float* __restrict__ x,     // [64][2048][13]
                        const float* __restrict__ eWih,  // [900][13]
                        const float* __restrict__ eWhh,  // [900][300]
                        const float* __restrict__ ebih,  // [900]
                        const float* __restrict__ ebhh,  // [900]
                        const float* __restrict__ fcW,   // [300][300]
                        const float* __restrict__ fcb,   // [300]
                        float* __restrict__ out) {
  __shared__ __align__(16) signed char hbuf[2][16][KI8];      // 10240 B
  __shared__ __align__(16) uint16_t    xt[2][16][32];         // 2048 B
  __shared__ __align__(16) float       scr[4][ROWS][NCOL];    // 19456 B
  __shared__ __align__(16) signed char wl56[5][1024];         // 5120 B
  __shared__ __align__(16) uint16_t    wx56[64][8];           // 1024 B

  const int tid = threadIdx.x, lane = tid & 63, w = tid >> 6;
  const int nl = lane & 15, q = lane >> 4;
  const int g = blockIdx.x;          // batch rows 4g..4g+3

  // ---- one-time: 7 register gate-blocks per wave (block b=7w+k) ----
  intx4   Bh[7][5];
  shortx8 Bx[7];
  float   bA[7], bB[7];
#pragma unroll
  for (int k = 0; k < 7; ++k) {
    int b = 7 * w + k, s = b / 3, gt = b - 3 * s;
    int jj = 16 * s + nl;
    bool jvv = (jj < EMB);
    int R = gt * EMB + (jvv ? jj : 0);
    for (int kt = 0; kt < 5; ++kt) {
      int bb[4] = {0, 0, 0, 0};
      for (int e = 0; e < 16; ++e) {
        int kk = kt * 64 + q * 16 + e;
        float v = (jvv && kk < EMB) ? eWhh[(size_t)R * EMB + kk] : 0.f;
        bb[e >> 2] |= (q8w(v) & 255) << ((e & 3) * 8);
      }
      intx4 t4; t4[0] = bb[0]; t4[1] = bb[1]; t4[2] = bb[2]; t4[3] = bb[3];
      Bh[k][kt] = t4;
    }
    union { uint16_t u[8]; shortx8 v; } c;
    for (int e = 0; e < 8; ++e) {
      int kk = q * 8 + e;
      c.u[e] = (jvv && kk < FEAT) ? f2b(eWih[R * FEAT + kk]) : (uint16_t)0;
    }
    Bx[k] = c.v;
    if (gt == 2) {
      bA[k] = jvv ? ebhh[2 * EMB + jj] : 0.f;   // hn bias
      bB[k] = jvv ? ebih[2 * EMB + jj] : 0.f;   // in bias
    } else {
      bA[k] = jvv ? (ebih[gt * EMB + jj] + ebhh[gt * EMB + jj]) : 0.f;
      bB[k] = 0.f;
    }
  }
  // block 56 (slice 18, n-gate) -> LDS, processed by wave 0
  float b56A = 0.f, b56B = 0.f;
  if (w == 0) {
    int jj = 288 + nl;
    bool jvv = (jj < EMB);
    int R = 2 * EMB + (jvv ? jj : 0);
    for (int kt = 0; kt < 5; ++kt)
      for (int e = 0; e < 16; ++e) {
        int kk = kt * 64 + q * 16 + e;
        float v = (jvv && kk < EMB) ? eWhh[(size_t)R * EMB + kk] : 0.f;
        wl56[kt][lane * 16 + e] = (signed char)q8w(v);
      }
    for (int e = 0; e < 8; ++e) {
      int kk = q * 8 + e;
      wx56[lane][e] = (jvv && kk < FEAT) ? f2b(eWih[R * FEAT + kk]) : (uint16_t)0;
    }
    b56A = jvv ? ebhh[2 * EMB + jj] : 0.f;
    b56B = jvv ? ebih[2 * EMB + jj] : 0.f;
  }

  // ---- init LDS: zero h/x buffers, then stage x_0 ----
  for (int i = tid; i < 2 * 16 * KI8; i += 512) ((signed char*)hbuf)[i] = 0;
  for (int i = tid; i < 2 * 16 * 32; i += 512) ((uint16_t*)xt)[i] = 0;
  __syncthreads();
  if (tid < ROWS * FEAT) {
    int m = tid / FEAT, f = tid - m * FEAT;
    xt[0][m][f] = f2b(x[((size_t)(g * ROWS + m) * TSTEPS) * FEAT + f]);
  }
  __syncthreads();

  float hprev[3] = {0.f, 0.f, 0.f};   // redistributed lane-resident h state

  // ================= recurrence: 2 barriers/step, all on-CU =================
  for (int t = 1; t <= TSTEPS; ++t) {
    const int p = (t - 1) & 1, pn = t & 1;

    // A fragments (shared by all this wave's blocks)
    intx4 Ah[5];
#pragma unroll
    for (int kt = 0; kt < 5; ++kt)
      Ah[kt] = *(const intx4*)&hbuf[p][nl][kt * 64 + q * 16];
    shortx8 Ax = *(const shortx8*)&xt[p][nl][q * 8];

    // wave 3: stage x_t for step t+1 (cheap, overlaps MFMA)
    if (w == 3 && lane < ROWS * FEAT && t < TSTEPS) {
      int m = lane / FEAT, f = lane - m * FEAT;
      xt[pn][m][f] = f2b(x[((size_t)(g * ROWS + m) * TSTEPS + t) * FEAT + f]);
    }

    // MFMA per block -> pre-activations (+bias) into scr (valid rows = q==0)
#pragma unroll
    for (int k = 0; k < 7; ++k) {
      int b = 7 * w + k, s = b / 3, gt = b - 3 * s;
      intx4 ai = {0, 0, 0, 0};
#pragma unroll
      for (int kt = 0; kt < 5; ++kt) ai = MFI8(Ah[kt], Bh[k][kt], ai);
      floatx4 ax = {0.f, 0.f, 0.f, 0.f};
      ax = MFBF(Ax, Bx[k], ax);
      if (q == 0) {
        int jj = 16 * s + nl;
        if (gt == 2) {
#pragma unroll
          for (int i = 0; i < 4; ++i) {
            scr[2][i][jj] = (float)ai[i] * SWH + bA[k];
            scr[3][i][jj] = ax[i] + bB[k];
          }
        } else {
#pragma unroll
          for (int i = 0; i < 4; ++i)
            scr[gt][i][jj] = (float)ai[i] * SWH + ax[i] + bA[k];
        }
      }
    }
    if (w == 0) {   // block 56 from LDS
      intx4 ai = {0, 0, 0, 0};
#pragma unroll
      for (int kt = 0; kt < 5; ++kt) {
        intx4 bb = *(const intx4*)&wl56[kt][lane * 16];
        ai = MFI8(Ah[kt], bb, ai);
      }
      shortx8 bx = *(const shortx8*)&wx56[lane][0];
      floatx4 ax = {0.f, 0.f, 0.f, 0.f};
      ax = MFBF(Ax, bx, ax);
      if (q == 0) {
        int jj = 288 + nl;
#pragma unroll
        for (int i = 0; i < 4; ++i) {
          scr[2][i][jj] = (float)ai[i] * SWH + b56A;
          scr[3][i][jj] = ax[i] + b56B;
        }
      }
    }
    __syncthreads();   // B1: scr complete

    // redistributed epilogue: lane owns elements e = tid + 512u
#pragma unroll
    for (int u = 0; u < 3; ++u) {
      int e = tid + u * 512;
      if (e < NELEM) {
        int col = e >> 2, row = e & 3;
        float pr  = scr[0][row][col];
        float pz  = scr[1][row][col];
        float hn  = scr[2][row][col];
        float in_ = scr[3][row][col];
        float r = sigf(pr), z = sigf(pz);
        float n = tanhf_(in_ + r * hn);
        float h = z * (hprev[u] - n) + n;
        hprev[u] = h;
        float hq = fminf(fmaxf(h * 127.f, -127.f), 127.f);
        hbuf[pn][row][col] = (signed char)__float2int_rn(hq);
      }
    }
    __syncthreads();   // B2: h_t complete
  }

  // ================= fc: emb = relu(h_T @ fcW^T + fcb) =================
  {
    float* oemb = out + (size_t)BATCH * TSTEPS * FEAT;
    intx4 AhT[5];
#pragma unroll
    for (int kt = 0; kt < 5; ++kt)
      AhT[kt] = *(const intx4*)&hbuf[0][nl][kt * 64 + q * 16];  // T even
    for (int u = 0; u < 3; ++u) {
      int s = w + u * 8;
      if (s >= 19) break;     // wave-uniform
      int jj = 16 * s + nl;
      bool jvv = (jj < EMB);
      intx4 acc = {0, 0, 0, 0};
      for (int kt = 0; kt < 5; ++kt) {
        int bb[4] = {0, 0, 0, 0};
        for (int e = 0; e < 16; ++e) {
          int kk = kt * 64 + q * 16 + e;
          float v = (jvv && kk < EMB) ? fcW[(size_t)jj * EMB + kk] : 0.f;
          bb[e >> 2] |= (q8w(v) & 255) << ((e & 3) * 8);
        }
        intx4 b4; b4[0] = bb[0]; b4[1] = bb[1]; b4[2] = bb[2]; b4[3] = bb[3];
        acc = MFI8(AhT[kt], b4, acc);
      }
      if (q == 0 && jvv) {
        float fb = fcb[jj];
#pragma unroll
        for (int i = 0; i < 4; ++i) {
          float e2 = (float)acc[i] * SWH + fb;
          oemb[(size_t)(g * ROWS + i) * EMB + jj] = e2 > 0.f ? e2 : 0.f;
        }
      }
    }
  }
}

// ---------------- decoder: 1 wave per batch, all fp32 (proven) --------------
__launch_bounds__(64, 1)
__global__ void gru_dec(const float* __restrict__ dWih,  // [39][300]
                        const float* __restrict__ dWhh,  // [39][13]
                        const float* __restrict__ dbih,  // [39]
                        const float* __restrict__ dbhh,  // [39]
                        float* __restrict__ out) {
  const int b  = blockIdx.x;
  const int lj = threadIdx.x;            // [0,13)=r [13,26)=z [26,39)=n
  const float* emb = out + (size_t)BATCH * TSTEPS * FEAT + (size_t)b * EMB;

  float Wd[FEAT];
#pragma unroll
  for (int k = 0; k < FEAT; ++k) Wd[k] = 0.f;
  float bhhv = 0.f, dgi = 0.f;
  if (lj < 3 * FEAT) {
#pragma unroll
    for (int k = 0; k < FEAT; ++k) Wd[k] = dWhh[lj * FEAT + k];
    bhhv = dbhh[lj];
    dgi  = dbih[lj];
#pragma unroll 4
    for (int k = 0; k < EMB; ++k)
      dgi = fmaf(emb[k], dWih[lj * EMB + k], dgi);
  }

  float hrep[FEAT];
#pragma unroll
  for (int k = 0; k < FEAT; ++k) hrep[k] = 0.f;
  float hown = 0.f;
  const bool nlane = (lj >= 2 * FEAT && lj < 3 * FEAT);
  float* orow = out + (size_t)b * TSTEPS * FEAT;

  for (int t = 0; t < TSTEPS; ++t) {
    float gh = bhhv;
#pragma unroll
    for (int k = 0; k < FEAT; ++k) gh = fmaf(Wd[k], hrep[k], gh);
    float sg = sigf(dgi + gh);
    float rr = __shfl(sg, (lj - 2 * FEAT) & 63);
    float zz = __shfl(sg, (lj - FEAT) & 63);
    float nn = tanhf_(dgi + rr * gh);
    float hn = zz * (hown - nn) + nn;
    bool same = (!nlane) || (hn == hown);
    if (nlane) {
      orow[t * FEAT + (lj - 2 * FEAT)] = hn;
      hown = hn;
    }
#pragma unroll
    for (int k = 0; k < FEAT; ++k) hrep[k] = __shfl(hown, 2 * FEAT + k);
    if (__all(same)) {  // exact fp32 fixed point -> rest constant
      if (nlane) {
        for (int t2 = t + 1; t2 < TSTEPS; ++t2)
          orow[t2 * FEAT + (lj - 2 * FEAT)] = hn;
      }
      break;
    }
  }
}

extern "C" void kernel_launch(void* const* d_in, const int* in_sizes, int n_in,
                              void* d_out, int out_size, void* d_ws, size_t ws_size,
                              hipStream_t stream) {
  (void)in_sizes; (void)n_in; (void)out_size; (void)d_ws; (void)ws_size;
  const float* x    = (const float*)d_in[0];
  const float* eWih = (const float*)d_in[1];
  const float* eWhh = (const float*)d_in[2];
  const float* ebih = (const float*)d_in[3];
  const float* ebhh = (const float*)d_in[4];
  const float* fcW  = (const float*)d_in[5];
  const float* fcb  = (const float*)d_in[6];
  const float* dWih = (const float*)d_in[7];
  const float* dWhh = (const float*)d_in[8];
  const float* dbih = (const float*)d_in[9];
  const float* dbhh = (const float*)d_in[10];

  hipLaunchKernelGGL(gru_enc, dim3(BATCH / ROWS), dim3(512), 0, stream,
                     x, eWih, eWhh, ebih, ebhh, fcW, fcb, (float*)d_out);
  hipLaunchKernelGGL(gru_dec, dim3(BATCH), dim3(64), 0, stream,
                     dWih, dWhh, dbih, dbhh, (float*)d_out);
}